// Round 5
// baseline (181.643 us; speedup 1.0000x reference)
//
#include <hip/hip_runtime.h>
#include <math.h>

#define Bb 8
#define Tt 2048
#define Cc 1024
#define Hh 64
#define BT (Bb * Tt)          // 16384 tokens
#define SLOG2E 0.18033688011112042f   // 0.125 * log2(e)

typedef __attribute__((ext_vector_type(8))) short short8;
typedef __attribute__((ext_vector_type(4))) float floatx4;

__device__ inline unsigned short f2bf(float f) {
  unsigned int u = __builtin_bit_cast(unsigned int, f);
  u += 0x7fff + ((u >> 16) & 1);   // RNE
  return (unsigned short)(u >> 16);
}
__device__ inline float bf2f(unsigned short u) {
  unsigned int x = ((unsigned int)u) << 16;
  return __builtin_bit_cast(float, x);
}

// ---------- Kernel 0: W fp32 [C][H] -> WT bf16 [192][C] (transposed) ----------
__global__ __launch_bounds__(256) void wconv(
    const float* __restrict__ Wq, const float* __restrict__ Wk,
    const float* __restrict__ Wv, unsigned short* __restrict__ WT) {
  __shared__ __align__(16) float Ttile[32][68];
  int bid = blockIdx.x;
  int w = bid >> 5;             // which W
  int c0 = (bid & 31) * 32;     // c-range
  const float* __restrict__ W = (w == 0) ? Wq : (w == 1 ? Wk : Wv);
  int t = threadIdx.x;
  {
    int i = t >> 3, h0 = (t & 7) * 8;
    float4 a = *(const float4*)&W[(size_t)(c0 + i) * Hh + h0];
    float4 b = *(const float4*)&W[(size_t)(c0 + i) * Hh + h0 + 4];
    *(float4*)&Ttile[i][h0] = a;
    *(float4*)&Ttile[i][h0 + 4] = b;
  }
  __syncthreads();
  int h = t >> 2, jj = t & 3;
  unsigned short tmp[8];
#pragma unroll
  for (int ii = 0; ii < 8; ++ii) tmp[ii] = f2bf(Ttile[jj * 8 + ii][h]);
  unsigned short* dst = &WT[(size_t)(w * 64 + h) * Cc + c0 + jj * 8];
  *(ushort4*)dst = make_ushort4(tmp[0], tmp[1], tmp[2], tmp[3]);
  *(ushort4*)(dst + 4) = make_ushort4(tmp[4], tmp[5], tmp[6], tmp[7]);
}

// ---------- Kernel 1: QKV projection, LDS-free direct-fragment streaming ----
// grid 512 blocks (M=32 token rows each), 512 threads (8 waves).
// Wave wv: m-sub = (wv&1)*16 rows, n-range = (wv>>1)*48 .. +47 (3 n16-groups).
// A-frags: two float4 from x + in-register f2bf (A[m=lrow][k=quad*8+j]).
// B-frags: contiguous 16B from WT[n][k] (B[k=quad*8+j][n=lrow]).
// No LDS, no barriers: pure global-load -> convert -> MFMA stream.
__global__ __launch_bounds__(512) void qkv4(
    const float* __restrict__ x, const unsigned short* __restrict__ WT,
    unsigned short* __restrict__ Qb, unsigned short* __restrict__ Kb,
    unsigned short* __restrict__ VTb) {
  int mt = blockIdx.x;
  int t = threadIdx.x;
  int wv = t >> 6, lane = t & 63;
  int lrow = lane & 15, quad = lane >> 4;
  int wm = wv & 1;          // m-sub (16 rows)
  int wn = wv >> 1;         // n-quarter (48 cols)

  floatx4 acc[3];
#pragma unroll
  for (int j = 0; j < 3; ++j)
#pragma unroll
    for (int r = 0; r < 4; ++r) acc[j][r] = 0.f;

  int row = mt * 32 + wm * 16 + lrow;          // this lane's A row (token)
  const float* xp = x + (size_t)row * Cc + quad * 8;
  const unsigned short* wp[3];
#pragma unroll
  for (int j = 0; j < 3; ++j)
    wp[j] = WT + (size_t)(wn * 48 + j * 16 + lrow) * Cc + quad * 8;

#pragma unroll 2
  for (int kk = 0; kk < 32; ++kk) {
    float4 v0 = *(const float4*)(xp + kk * 32);
    float4 v1 = *(const float4*)(xp + kk * 32 + 4);
    short8 a;
    a[0] = (short)f2bf(v0.x); a[1] = (short)f2bf(v0.y);
    a[2] = (short)f2bf(v0.z); a[3] = (short)f2bf(v0.w);
    a[4] = (short)f2bf(v1.x); a[5] = (short)f2bf(v1.y);
    a[6] = (short)f2bf(v1.z); a[7] = (short)f2bf(v1.w);
#pragma unroll
    for (int j = 0; j < 3; ++j) {
      short8 b = *(const short8*)(wp[j] + kk * 32);
      acc[j] = __builtin_amdgcn_mfma_f32_16x16x32_bf16(a, b, acc[j], 0, 0, 0);
    }
  }

  // epilogue: D row(m) = quad*4+r, col(n) = lrow
  int tok0 = mt * 32 + wm * 16 + quad * 4;
#pragma unroll
  for (int j = 0; j < 3; ++j) {
    int nbase = wn * 48 + j * 16;
    if (nbase >= 128) {
      int h = nbase - 128 + lrow;
      *(ushort4*)&VTb[(size_t)h * BT + tok0] =
          make_ushort4(f2bf(acc[j][0]), f2bf(acc[j][1]),
                       f2bf(acc[j][2]), f2bf(acc[j][3]));
    } else {
      unsigned short* dst = (nbase >= 64) ? Kb : Qb;
      int col = (nbase & 63) + lrow;
#pragma unroll
      for (int r = 0; r < 4; ++r)
        dst[(size_t)(tok0 + r) * Hh + col] = f2bf(acc[j][r]);
    }
  }
}

// ---------- Kernel 2: causal attention, no-max softmax, frag loads from global ----------
// grid 256 blocks (b, j), 512 threads (8 waves). Block handles query tiles
// j and 63-j sequentially; each tile's key blocks (64 keys) are split 8-way
// across waves (wave wv takes kt = wv, wv+8, ...). No barriers in K-loop.
// Unnormalized softmax: P = exp2(S*scale*log2e) (bounded: |S*scale| <~ 54),
// l via ones-column MFMA. Partials combined through LDS (bf16 O + fp32 l).
__global__ __launch_bounds__(512) void attn3(
    const unsigned short* __restrict__ Qb, const unsigned short* __restrict__ Kb,
    const unsigned short* __restrict__ VTb, float* __restrict__ out) {
  // [0,32K): per-wave P scratch (wv*4096 B) during compute; combine-O after.
  // [32K, 33K): l partials [8 waves][32 queries] fp32.
  __shared__ __align__(16) unsigned char smem[33 * 1024];
  unsigned short* Pall = (unsigned short*)smem;
  unsigned short* Ocomb = (unsigned short*)smem;
  float* Lcomb = (float*)(smem + 32768);

  int bid = blockIdx.x;
  int b = bid >> 5;
  int j = bid & 31;
  int t = threadIdx.x;
  int wv = t >> 6, lane = t & 63;
  int lrow = lane & 15, quad = lane >> 4;

  unsigned short* Pw = Pall + wv * 2048;   // this wave's 4KB P scratch

  short8 ones;
#pragma unroll
  for (int i = 0; i < 8; ++i) ones[i] = (short)0x3F80;   // bf16 1.0

  for (int half = 0; half < 2; ++half) {
    int qt = half ? (63 - j) : j;
    int q0 = qt * 32;
    int nkt = (qt >> 1) + 1;

    // Q A-frags: A[m=lrow][k=quad*8+jj], direct from global
    short8 aq[2][2];
#pragma unroll
    for (int qs = 0; qs < 2; ++qs)
#pragma unroll
      for (int kc = 0; kc < 2; ++kc)
        aq[qs][kc] = *(const short8*)
            &Qb[(size_t)(b * Tt + q0 + qs * 16 + lrow) * Hh + kc * 32 + quad * 8];

    floatx4 acc_o[2][4];
    floatx4 acc_l[2];
#pragma unroll
    for (int qs = 0; qs < 2; ++qs) {
#pragma unroll
      for (int r = 0; r < 4; ++r) acc_l[qs][r] = 0.f;
#pragma unroll
      for (int hs = 0; hs < 4; ++hs)
#pragma unroll
        for (int r = 0; r < 4; ++r) acc_o[qs][hs][r] = 0.f;
    }

    for (int kt = wv; kt < nkt; kt += 8) {
      int kbase = b * Tt + kt * 64;
      // K B-frags (S): lane(n=lrow key, quad k-chunk) reads 16B from Kb row
      short8 kf[4][2], vf[4][2];
#pragma unroll
      for (int sn = 0; sn < 4; ++sn)
#pragma unroll
        for (int kc = 0; kc < 2; ++kc)
          kf[sn][kc] = *(const short8*)
              &Kb[(size_t)(kbase + sn * 16 + lrow) * Hh + kc * 32 + quad * 8];
      // VT B-frags (PV): lane(n=lrow h, quad tok-chunk) reads 16B from VTb row
#pragma unroll
      for (int hs = 0; hs < 4; ++hs)
#pragma unroll
        for (int kc = 0; kc < 2; ++kc)
          vf[hs][kc] = *(const short8*)
              &VTb[(size_t)(hs * 16 + lrow) * BT + kbase + kc * 32 + quad * 8];

      // S = Q K^T (16 MFMAs)
      floatx4 s[2][4];
#pragma unroll
      for (int qs = 0; qs < 2; ++qs)
#pragma unroll
        for (int sn = 0; sn < 4; ++sn) {
          floatx4 z;
#pragma unroll
          for (int r = 0; r < 4; ++r) z[r] = 0.f;
          z = __builtin_amdgcn_mfma_f32_16x16x32_bf16(aq[qs][0], kf[sn][0], z, 0, 0, 0);
          z = __builtin_amdgcn_mfma_f32_16x16x32_bf16(aq[qs][1], kf[sn][1], z, 0, 0, 0);
          s[qs][sn] = z;
        }

      // mask (diagonal block only) + exp2 + write P to reader-linear LDS
      bool diag = (kt == nkt - 1);
#pragma unroll
      for (int qs = 0; qs < 2; ++qs)
#pragma unroll
        for (int sn = 0; sn < 4; ++sn) {
          int k5 = (sn & 1) * 16 + lrow;            // key within 32-chunk
          int slot = qs * 2 + (sn >> 1);            // A-frag slot
          int rlbase = (k5 >> 3) * 16;              // reader-lane base
#pragma unroll
          for (int r = 0; r < 4; ++r) {
            float v = s[qs][sn][r] * SLOG2E;
            if (diag) {
              int gk = kt * 64 + sn * 16 + lrow;
              int gq = q0 + qs * 16 + quad * 4 + r;
              if (gk > gq) v = -INFINITY;
            }
            float p = exp2f(v);
            Pw[slot * 512 + (rlbase + quad * 4 + r) * 8 + (k5 & 7)] = f2bf(p);
          }
        }

      // P A-frags: linear per-lane read (conflict-free)
      short8 ap[2][2];
#pragma unroll
      for (int qs = 0; qs < 2; ++qs)
#pragma unroll
        for (int kc = 0; kc < 2; ++kc)
          ap[qs][kc] = *(const short8*)&Pw[(qs * 2 + kc) * 512 + lane * 8];

      // l += P * ones ; O += P * V (20 MFMAs)
#pragma unroll
      for (int qs = 0; qs < 2; ++qs) {
        acc_l[qs] = __builtin_amdgcn_mfma_f32_16x16x32_bf16(ap[qs][0], ones, acc_l[qs], 0, 0, 0);
        acc_l[qs] = __builtin_amdgcn_mfma_f32_16x16x32_bf16(ap[qs][1], ones, acc_l[qs], 0, 0, 0);
#pragma unroll
        for (int hs = 0; hs < 4; ++hs) {
          acc_o[qs][hs] = __builtin_amdgcn_mfma_f32_16x16x32_bf16(ap[qs][0], vf[hs][0], acc_o[qs][hs], 0, 0, 0);
          acc_o[qs][hs] = __builtin_amdgcn_mfma_f32_16x16x32_bf16(ap[qs][1], vf[hs][1], acc_o[qs][hs], 0, 0, 0);
        }
      }
    }

    // ---- combine partials ----
    // O partial bf16: wave writes its own region (same bytes as its P scratch)
#pragma unroll
    for (int qs = 0; qs < 2; ++qs)
#pragma unroll
      for (int hs = 0; hs < 4; ++hs) {
        int s8 = qs * 4 + hs;
        *(ushort4*)&Ocomb[((wv * 8 + s8) * 64 + lane) * 4] =
            make_ushort4(f2bf(acc_o[qs][hs][0]), f2bf(acc_o[qs][hs][1]),
                         f2bf(acc_o[qs][hs][2]), f2bf(acc_o[qs][hs][3]));
      }
    if (lrow == 0) {
#pragma unroll
      for (int qs = 0; qs < 2; ++qs)
#pragma unroll
        for (int r = 0; r < 4; ++r)
          Lcomb[wv * 32 + qs * 16 + quad * 4 + r] = acc_l[qs][r];
    }
    __syncthreads();

    // reduce: thread (slot=wv, lane) sums 8 wave-partials and stores
    {
      int qsub = wv >> 2, hs = wv & 3;
      float o[4] = {0.f, 0.f, 0.f, 0.f};
#pragma unroll
      for (int w = 0; w < 8; ++w) {
        ushort4 pk = *(const ushort4*)&Ocomb[((w * 8 + wv) * 64 + lane) * 4];
        o[0] += bf2f(pk.x); o[1] += bf2f(pk.y);
        o[2] += bf2f(pk.z); o[3] += bf2f(pk.w);
      }
#pragma unroll
      for (int r = 0; r < 4; ++r) {
        float lv = 0.f;
#pragma unroll
        for (int w = 0; w < 8; ++w)
          lv += Lcomb[w * 32 + qsub * 16 + quad * 4 + r];
        int row = q0 + qsub * 16 + quad * 4 + r;
        out[(size_t)(b * Tt + row) * Hh + hs * 16 + lrow] = o[r] / lv;
      }
    }
    __syncthreads();   // before next half reuses P/O region
  }
}

extern "C" void kernel_launch(void* const* d_in, const int* in_sizes, int n_in,
                              void* d_out, int out_size, void* d_ws, size_t ws_size,
                              hipStream_t stream) {
  const float* x = (const float*)d_in[0];
  const float* Wq = (const float*)d_in[1];
  const float* Wk = (const float*)d_in[2];
  const float* Wv = (const float*)d_in[3];
  float* out = (float*)d_out;

  unsigned short* WT = (unsigned short*)d_ws;          // [192][1024]
  unsigned short* Qb = WT + 192 * 1024;                // [BT][64]
  unsigned short* Kb = Qb + (size_t)BT * Hh;           // [BT][64]
  unsigned short* VTb = Kb + (size_t)BT * Hh;          // [64][BT]

  wconv<<<dim3(96), dim3(256), 0, stream>>>(Wq, Wk, Wv, WT);
  qkv4<<<dim3(512), dim3(512), 0, stream>>>(x, WT, Qb, Kb, VTb);
  attn3<<<dim3(256), dim3(512), 0, stream>>>(Qb, Kb, VTb, out);
}

// Round 6
// 131.751 us; speedup vs baseline: 1.3787x; 1.3787x over previous
//
#include <hip/hip_runtime.h>
#include <math.h>

#define Bb 8
#define Tt 2048
#define Cc 1024
#define Hh 64
#define BT (Bb * Tt)          // 16384 tokens
#define SLOG2E 0.18033688011112042f   // 0.125 * log2(e)

typedef __attribute__((ext_vector_type(8))) short short8;
typedef __attribute__((ext_vector_type(4))) float floatx4;

__device__ inline unsigned short f2bf(float f) {
  unsigned int u = __builtin_bit_cast(unsigned int, f);
  u += 0x7fff + ((u >> 16) & 1);   // RNE
  return (unsigned short)(u >> 16);
}
__device__ inline float bf2f(unsigned short u) {
  unsigned int x = ((unsigned int)u) << 16;
  return __builtin_bit_cast(float, x);
}

// ---------- Kernel 0: W fp32 [C][H] -> WTf bf16 fragment-major ----------
// WTf element (n in 0..191, k in 0..1023) at
//   ((g*32 + kc)*64 + quad*16 + lrow)*8 + j
// with g=n>>4, lrow=n&15, kc=k>>5, quad=(k>>3)&3, j=k&7.
// So a B-frag load in qkv is base + lane*8 ushorts: lane-linear, coalesced.
__global__ __launch_bounds__(256) void wconv2(
    const float* __restrict__ Wq, const float* __restrict__ Wk,
    const float* __restrict__ Wv, unsigned short* __restrict__ WTf) {
  int bid = blockIdx.x;
  int w = bid >> 5;            // which W
  int kc = bid & 31;           // 32-k chunk
  const float* __restrict__ W = (w == 0) ? Wq : (w == 1 ? Wk : Wv);
  int t = threadIdx.x;
  int hg = t >> 6, quad = (t >> 4) & 3, lrow = t & 15;
  int g = w * 4 + hg;
  int h = hg * 16 + lrow;
  unsigned short tmp[8];
#pragma unroll
  for (int j = 0; j < 8; ++j)
    tmp[j] = f2bf(W[(size_t)(kc * 32 + quad * 8 + j) * Hh + h]);
  unsigned short* dst = &WTf[((size_t)(g * 32 + kc) * 64 + quad * 16 + lrow) * 8];
  *(ushort4*)dst = make_ushort4(tmp[0], tmp[1], tmp[2], tmp[3]);
  *(ushort4*)(dst + 4) = make_ushort4(tmp[4], tmp[5], tmp[6], tmp[7]);
}

// ---------- Kernel 1: QKV projection ----------
// grid 512 (M=32 token rows), 256 threads (4 waves). BK=64, 16 k-steps.
// A (x) staged in LDS, frag-major with rotate swizzle ml'=(ml+quad+4*kc)&15:
// both ds_write_b128 (staging) and ds_read_b128 (frags) are conflict-free.
// B frags load lane-linear from prepacked WTf (global, L2-resident).
// Wave wv covers both m-subs and n16-groups wv*3..wv*3+2 (12 MFMAs/step).
__global__ __launch_bounds__(256) void qkv5(
    const float* __restrict__ x, const unsigned short* __restrict__ WTf,
    unsigned short* __restrict__ Qb, unsigned short* __restrict__ Kb,
    unsigned short* __restrict__ VTt) {
  __shared__ __align__(16) unsigned short Af[2048];   // 4 KB

  int mt = blockIdx.x;
  int t = threadIdx.x;
  int wv = t >> 6, lane = t & 63;
  int lrow = lane & 15, quad = lane >> 4;

  floatx4 acc[2][3];   // [m-sub][n-group]
#pragma unroll
  for (int g2 = 0; g2 < 2; ++g2)
#pragma unroll
    for (int j = 0; j < 3; ++j)
#pragma unroll
      for (int r = 0; r < 4; ++r) acc[g2][j][r] = 0.f;

  // staging coords: thread covers (row srow, k-chunk scg of 8)
  int srow = t >> 3, scg = t & 7;
  int skc2 = scg >> 2, squad = scg & 3;
  int sslot = ((srow >> 4) * 2 + skc2) * 64 + squad * 16 +
              (((srow & 15) + squad + 4 * skc2) & 15);
  const float* xp = x + (size_t)(mt * 32 + srow) * Cc + scg * 8;

  // frag-read slots (swizzled)
  int aslot[2][2];
#pragma unroll
  for (int g2 = 0; g2 < 2; ++g2)
#pragma unroll
    for (int kc2 = 0; kc2 < 2; ++kc2)
      aslot[g2][kc2] = ((g2 * 2 + kc2) * 64 + quad * 16 +
                        ((lrow + quad + 4 * kc2) & 15)) * 8;

  const unsigned short* wbase[3];
#pragma unroll
  for (int j = 0; j < 3; ++j)
    wbase[j] = WTf + (size_t)(wv * 3 + j) * 32 * 512 + lane * 8;

  float4 nv0 = *(const float4*)xp;
  float4 nv1 = *(const float4*)(xp + 4);

  for (int kk = 0; kk < 16; ++kk) {
    __syncthreads();   // prior frag reads done before overwrite
    short8 a;
    a[0] = (short)f2bf(nv0.x); a[1] = (short)f2bf(nv0.y);
    a[2] = (short)f2bf(nv0.z); a[3] = (short)f2bf(nv0.w);
    a[4] = (short)f2bf(nv1.x); a[5] = (short)f2bf(nv1.y);
    a[6] = (short)f2bf(nv1.z); a[7] = (short)f2bf(nv1.w);
    *(short8*)&Af[sslot * 8] = a;
    if (kk < 15) {   // prefetch next step's x across the compute phase
      nv0 = *(const float4*)(xp + (kk + 1) * 64);
      nv1 = *(const float4*)(xp + (kk + 1) * 64 + 4);
    }
    __syncthreads();

    short8 bf[3][2];
    int kg = kk * 2;
#pragma unroll
    for (int j = 0; j < 3; ++j)
#pragma unroll
      for (int kc2 = 0; kc2 < 2; ++kc2)
        bf[j][kc2] = *(const short8*)(wbase[j] + (size_t)(kg + kc2) * 512);
    short8 af[2][2];
#pragma unroll
    for (int g2 = 0; g2 < 2; ++g2)
#pragma unroll
      for (int kc2 = 0; kc2 < 2; ++kc2)
        af[g2][kc2] = *(const short8*)&Af[aslot[g2][kc2]];
#pragma unroll
    for (int g2 = 0; g2 < 2; ++g2)
#pragma unroll
      for (int j = 0; j < 3; ++j) {
        acc[g2][j] = __builtin_amdgcn_mfma_f32_16x16x32_bf16(af[g2][0], bf[j][0], acc[g2][j], 0, 0, 0);
        acc[g2][j] = __builtin_amdgcn_mfma_f32_16x16x32_bf16(af[g2][1], bf[j][1], acc[g2][j], 0, 0, 0);
      }
  }

  // epilogue: D row(m)=quad*4+r, col(n)=lrow
#pragma unroll
  for (int g2 = 0; g2 < 2; ++g2) {
    int tok0 = mt * 32 + g2 * 16 + quad * 4;
#pragma unroll
    for (int j = 0; j < 3; ++j) {
      int nbase = (wv * 3 + j) * 16;
      if (nbase >= 128) {
        int h = nbase - 128 + lrow;
        // VTt: per-64-token tile, [ktile][h][tok&63], rows 128 B apart
        *(ushort4*)&VTt[(size_t)(tok0 >> 6) * 4096 + h * 64 + (tok0 & 63)] =
            make_ushort4(f2bf(acc[g2][j][0]), f2bf(acc[g2][j][1]),
                         f2bf(acc[g2][j][2]), f2bf(acc[g2][j][3]));
      } else {
        unsigned short* dst = (nbase >= 64) ? Kb : Qb;
        int col = (nbase & 63) + lrow;
#pragma unroll
        for (int r = 0; r < 4; ++r)
          dst[(size_t)(tok0 + r) * Hh + col] = f2bf(acc[g2][j][r]);
      }
    }
  }
}

// ---------- Kernel 2: causal attention, no-max softmax ----------
// grid 256 blocks (b, j), 512 threads (8 waves). Block handles query tiles
// j and 63-j sequentially; key blocks split 8-way across waves; no barriers
// in K-loop. Unnormalized softmax P = exp2(S*scale*log2e); l via ones-MFMA.
__global__ __launch_bounds__(512) void attn3(
    const unsigned short* __restrict__ Qb, const unsigned short* __restrict__ Kb,
    const unsigned short* __restrict__ VTt, float* __restrict__ out) {
  __shared__ __align__(16) unsigned char smem[33 * 1024];
  unsigned short* Pall = (unsigned short*)smem;
  unsigned short* Ocomb = (unsigned short*)smem;
  float* Lcomb = (float*)(smem + 32768);

  int bid = blockIdx.x;
  int b = bid >> 5;
  int j = bid & 31;
  int t = threadIdx.x;
  int wv = t >> 6, lane = t & 63;
  int lrow = lane & 15, quad = lane >> 4;

  unsigned short* Pw = Pall + wv * 2048;

  short8 ones;
#pragma unroll
  for (int i = 0; i < 8; ++i) ones[i] = (short)0x3F80;

  for (int half = 0; half < 2; ++half) {
    int qt = half ? (63 - j) : j;
    int q0 = qt * 32;
    int nkt = (qt >> 1) + 1;

    short8 aq[2][2];
#pragma unroll
    for (int qs = 0; qs < 2; ++qs)
#pragma unroll
      for (int kc = 0; kc < 2; ++kc)
        aq[qs][kc] = *(const short8*)
            &Qb[(size_t)(b * Tt + q0 + qs * 16 + lrow) * Hh + kc * 32 + quad * 8];

    floatx4 acc_o[2][4];
    floatx4 acc_l[2];
#pragma unroll
    for (int qs = 0; qs < 2; ++qs) {
#pragma unroll
      for (int r = 0; r < 4; ++r) acc_l[qs][r] = 0.f;
#pragma unroll
      for (int hs = 0; hs < 4; ++hs)
#pragma unroll
        for (int r = 0; r < 4; ++r) acc_o[qs][hs][r] = 0.f;
    }

    for (int kt = wv; kt < nkt; kt += 8) {
      int kbase = b * Tt + kt * 64;
      short8 kf[4][2], vf[4][2];
#pragma unroll
      for (int sn = 0; sn < 4; ++sn)
#pragma unroll
        for (int kc = 0; kc < 2; ++kc)
          kf[sn][kc] = *(const short8*)
              &Kb[(size_t)(kbase + sn * 16 + lrow) * Hh + kc * 32 + quad * 8];
      int ktile = b * 32 + kt;
#pragma unroll
      for (int hs = 0; hs < 4; ++hs)
#pragma unroll
        for (int kc = 0; kc < 2; ++kc)
          vf[hs][kc] = *(const short8*)
              &VTt[(size_t)ktile * 4096 + (hs * 16 + lrow) * 64 + kc * 32 + quad * 8];

      floatx4 s[2][4];
#pragma unroll
      for (int qs = 0; qs < 2; ++qs)
#pragma unroll
        for (int sn = 0; sn < 4; ++sn) {
          floatx4 z;
#pragma unroll
          for (int r = 0; r < 4; ++r) z[r] = 0.f;
          z = __builtin_amdgcn_mfma_f32_16x16x32_bf16(aq[qs][0], kf[sn][0], z, 0, 0, 0);
          z = __builtin_amdgcn_mfma_f32_16x16x32_bf16(aq[qs][1], kf[sn][1], z, 0, 0, 0);
          s[qs][sn] = z;
        }

      bool diag = (kt == nkt - 1);
#pragma unroll
      for (int qs = 0; qs < 2; ++qs)
#pragma unroll
        for (int sn = 0; sn < 4; ++sn) {
          int k5 = (sn & 1) * 16 + lrow;
          int slot = qs * 2 + (sn >> 1);
          int rlbase = (k5 >> 3) * 16;
#pragma unroll
          for (int r = 0; r < 4; ++r) {
            float v = s[qs][sn][r] * SLOG2E;
            if (diag) {
              int gk = kt * 64 + sn * 16 + lrow;
              int gq = q0 + qs * 16 + quad * 4 + r;
              if (gk > gq) v = -INFINITY;
            }
            float p = exp2f(v);
            Pw[slot * 512 + (rlbase + quad * 4 + r) * 8 + (k5 & 7)] = f2bf(p);
          }
        }

      short8 ap[2][2];
#pragma unroll
      for (int qs = 0; qs < 2; ++qs)
#pragma unroll
        for (int kc = 0; kc < 2; ++kc)
          ap[qs][kc] = *(const short8*)&Pw[(qs * 2 + kc) * 512 + lane * 8];

#pragma unroll
      for (int qs = 0; qs < 2; ++qs) {
        acc_l[qs] = __builtin_amdgcn_mfma_f32_16x16x32_bf16(ap[qs][0], ones, acc_l[qs], 0, 0, 0);
        acc_l[qs] = __builtin_amdgcn_mfma_f32_16x16x32_bf16(ap[qs][1], ones, acc_l[qs], 0, 0, 0);
#pragma unroll
        for (int hs = 0; hs < 4; ++hs) {
          acc_o[qs][hs] = __builtin_amdgcn_mfma_f32_16x16x32_bf16(ap[qs][0], vf[hs][0], acc_o[qs][hs], 0, 0, 0);
          acc_o[qs][hs] = __builtin_amdgcn_mfma_f32_16x16x32_bf16(ap[qs][1], vf[hs][1], acc_o[qs][hs], 0, 0, 0);
        }
      }
    }

    // ---- combine partials ----
#pragma unroll
    for (int qs = 0; qs < 2; ++qs)
#pragma unroll
      for (int hs = 0; hs < 4; ++hs) {
        int s8 = qs * 4 + hs;
        *(ushort4*)&Ocomb[((wv * 8 + s8) * 64 + lane) * 4] =
            make_ushort4(f2bf(acc_o[qs][hs][0]), f2bf(acc_o[qs][hs][1]),
                         f2bf(acc_o[qs][hs][2]), f2bf(acc_o[qs][hs][3]));
      }
    if (lrow == 0) {
#pragma unroll
      for (int qs = 0; qs < 2; ++qs)
#pragma unroll
        for (int r = 0; r < 4; ++r)
          Lcomb[wv * 32 + qs * 16 + quad * 4 + r] = acc_l[qs][r];
    }
    __syncthreads();

    {
      int qsub = wv >> 2, hs = wv & 3;
      float o[4] = {0.f, 0.f, 0.f, 0.f};
#pragma unroll
      for (int w = 0; w < 8; ++w) {
        ushort4 pk = *(const ushort4*)&Ocomb[((w * 8 + wv) * 64 + lane) * 4];
        o[0] += bf2f(pk.x); o[1] += bf2f(pk.y);
        o[2] += bf2f(pk.z); o[3] += bf2f(pk.w);
      }
#pragma unroll
      for (int r = 0; r < 4; ++r) {
        float lv = 0.f;
#pragma unroll
        for (int w = 0; w < 8; ++w)
          lv += Lcomb[w * 32 + qsub * 16 + quad * 4 + r];
        int row = q0 + qsub * 16 + quad * 4 + r;
        out[(size_t)(b * Tt + row) * Hh + hs * 16 + lrow] = o[r] / lv;
      }
    }
    __syncthreads();
  }
}

extern "C" void kernel_launch(void* const* d_in, const int* in_sizes, int n_in,
                              void* d_out, int out_size, void* d_ws, size_t ws_size,
                              hipStream_t stream) {
  const float* x = (const float*)d_in[0];
  const float* Wq = (const float*)d_in[1];
  const float* Wk = (const float*)d_in[2];
  const float* Wv = (const float*)d_in[3];
  float* out = (float*)d_out;

  unsigned short* WTf = (unsigned short*)d_ws;         // 192*1024 frag-major
  unsigned short* Qb = WTf + 192 * 1024;               // [BT][64]
  unsigned short* Kb = Qb + (size_t)BT * Hh;           // [BT][64]
  unsigned short* VTt = Kb + (size_t)BT * Hh;          // [BT/64][64][64]

  wconv2<<<dim3(96), dim3(256), 0, stream>>>(Wq, Wk, Wv, WTf);
  qkv5<<<dim3(512), dim3(256), 0, stream>>>(x, WTf, Qb, Kb, VTt);
  attn3<<<dim3(256), dim3(512), 0, stream>>>(Qb, Kb, VTt, out);
}